// Round 3
// baseline (378.753 us; speedup 1.0000x reference)
//
#include <hip/hip_runtime.h>
#include <hip/hip_bf16.h>
#include <stdint.h>

__device__ __forceinline__ int imin(int a, int b) { return a < b ? a : b; }
__device__ __forceinline__ int imax(int a, int b) { return a > b ? a : b; }

#define TMASK ((1u << 19) - 1u)

__global__ void __launch_bounds__(256) ngp_main(
    const float* __restrict__ xin,
    const float* __restrict__ din,
    const float2* __restrict__ tab,     // [L][T] pairs (F=2), f32
    const float* __restrict__ W1,      // [32][64]
    const float* __restrict__ W2,      // [64][16]
    const float* __restrict__ WIN,     // [32][64]
    const float* __restrict__ WH,      // [64][64]
    const float* __restrict__ WOUT,    // [64][3]
    float* __restrict__ out,
    int n)
{
    const int i = blockIdx.x * 256 + threadIdx.x;
    if (i >= n) return;

    constexpr int RES[16] = {16, 23, 31, 43, 59, 81, 112, 154,
                             213, 295, 407, 562, 777, 1073, 1483, 2048};

    // ---- position -> [0,1] ----
    const float xn0 = (xin[3 * i + 0] + 1.0f) * 0.5f;
    const float xn1 = (xin[3 * i + 1] + 1.0f) * 0.5f;
    const float xn2 = (xin[3 * i + 2] + 1.0f) * 0.5f;

    // ---- hash encode fused into first density layer: h1 += enc @ W1 ----
    float h1[64];
    #pragma unroll
    for (int j = 0; j < 64; ++j) h1[j] = 0.0f;

    #pragma unroll
    for (int l = 0; l < 16; ++l) {
        const int rm = RES[l] - 1;
        const float rf = (float)rm;
        const float p0 = xn0 * rf, p1 = xn1 * rf, p2 = xn2 * rf;
        const float f0 = floorf(p0), f1 = floorf(p1), f2 = floorf(p2);
        const int i0 = (int)f0, i1 = (int)f1, i2 = (int)f2;
        const float w0 = p0 - f0, w1 = p1 - f1, w2 = p2 - f2;

        const int a0 = imax(imin(i0, rm), 0), b0 = imax(imin(i0 + 1, rm), 0);
        const int a1 = imax(imin(i1, rm), 0), b1 = imax(imin(i1 + 1, rm), 0);
        const int a2 = imax(imin(i2, rm), 0), b2 = imax(imin(i2 + 1, rm), 0);

        const uint32_t t0a = (uint32_t)a0;
        const uint32_t t0b = (uint32_t)b0;
        const uint32_t t1a = (uint32_t)a1 * 2654435761u;
        const uint32_t t1b = (uint32_t)b1 * 2654435761u;
        const uint32_t t2a = (uint32_t)a2 * 805459861u;
        const uint32_t t2b = (uint32_t)b2 * 805459861u;
        const uint32_t base = (uint32_t)l << 19;

        const float2 v000 = tab[base + ((t0a ^ t1a ^ t2a) & TMASK)];
        const float2 v100 = tab[base + ((t0b ^ t1a ^ t2a) & TMASK)];
        const float2 v010 = tab[base + ((t0a ^ t1b ^ t2a) & TMASK)];
        const float2 v110 = tab[base + ((t0b ^ t1b ^ t2a) & TMASK)];
        const float2 v001 = tab[base + ((t0a ^ t1a ^ t2b) & TMASK)];
        const float2 v101 = tab[base + ((t0b ^ t1a ^ t2b) & TMASK)];
        const float2 v011 = tab[base + ((t0a ^ t1b ^ t2b) & TMASK)];
        const float2 v111 = tab[base + ((t0b ^ t1b ^ t2b) & TMASK)];

        const float u0 = 1.0f - w0, u1 = 1.0f - w1, u2 = 1.0f - w2;
        float e0 = 0.0f, e1 = 0.0f;
        {   float cw = u0 * u1 * u2;  e0 = fmaf(v000.x, cw, e0); e1 = fmaf(v000.y, cw, e1); }
        {   float cw = w0 * u1 * u2;  e0 = fmaf(v100.x, cw, e0); e1 = fmaf(v100.y, cw, e1); }
        {   float cw = u0 * w1 * u2;  e0 = fmaf(v010.x, cw, e0); e1 = fmaf(v010.y, cw, e1); }
        {   float cw = w0 * w1 * u2;  e0 = fmaf(v110.x, cw, e0); e1 = fmaf(v110.y, cw, e1); }
        {   float cw = u0 * u1 * w2;  e0 = fmaf(v001.x, cw, e0); e1 = fmaf(v001.y, cw, e1); }
        {   float cw = w0 * u1 * w2;  e0 = fmaf(v101.x, cw, e0); e1 = fmaf(v101.y, cw, e1); }
        {   float cw = u0 * w1 * w2;  e0 = fmaf(v011.x, cw, e0); e1 = fmaf(v011.y, cw, e1); }
        {   float cw = w0 * w1 * w2;  e0 = fmaf(v111.x, cw, e0); e1 = fmaf(v111.y, cw, e1); }

        #pragma unroll
        for (int j = 0; j < 64; ++j)
            h1[j] = fmaf(e0, W1[(2 * l) * 64 + j], fmaf(e1, W1[(2 * l + 1) * 64 + j], h1[j]));
    }

    // ---- density layer 2: h = relu(h1) @ W2 ----
    float h[16];
    #pragma unroll
    for (int j = 0; j < 16; ++j) h[j] = 0.0f;
    #pragma unroll
    for (int k = 0; k < 64; ++k) {
        const float v = fmaxf(h1[k], 0.0f);
        #pragma unroll
        for (int j = 0; j < 16; ++j) h[j] = fmaf(v, W2[k * 16 + j], h[j]);
    }

    out[i] = __expf(h[0]);   // sigma

    // ---- SH degree 4 ----
    const float dx = din[3 * i + 0];
    const float dy = din[3 * i + 1];
    const float dz = din[3 * i + 2];
    const float xy = dx * dy, xz = dx * dz, yz = dy * dz;
    const float x2 = dx * dx, y2 = dy * dy, z2 = dz * dz;

    float sh[16];
    sh[0]  = 0.28209479177387814f;
    sh[1]  = -0.48860251190291987f * dy;
    sh[2]  = 0.48860251190291987f * dz;
    sh[3]  = -0.48860251190291987f * dx;
    sh[4]  = 1.0925484305920792f * xy;
    sh[5]  = -1.0925484305920792f * yz;
    sh[6]  = 0.94617469575756f * z2 - 0.31539156525252f;
    sh[7]  = -1.0925484305920792f * xz;
    sh[8]  = 0.5462742152960396f * (x2 - y2);
    sh[9]  = 0.5900435899266435f * dy * (-3.0f * x2 + y2);
    sh[10] = 2.890611442640554f * xy * dz;
    sh[11] = 0.4570457994644657f * dy * (1.0f - 5.0f * z2);
    sh[12] = 0.3731763325901154f * dz * (5.0f * z2 - 3.0f);
    sh[13] = 0.4570457994644657f * dx * (1.0f - 5.0f * z2);
    sh[14] = 1.445305721320277f * dz * (x2 - y2);
    sh[15] = 0.5900435899266435f * dx * (-x2 + 3.0f * y2);

    // ---- color layer 1: a = relu([sh, h] @ WIN) ----
    float av[64];
    #pragma unroll
    for (int j = 0; j < 64; ++j) av[j] = 0.0f;
    #pragma unroll
    for (int k = 0; k < 16; ++k) {
        const float v = sh[k];
        #pragma unroll
        for (int j = 0; j < 64; ++j) av[j] = fmaf(v, WIN[k * 64 + j], av[j]);
    }
    #pragma unroll
    for (int k = 0; k < 16; ++k) {
        const float v = h[k];
        #pragma unroll
        for (int j = 0; j < 64; ++j) av[j] = fmaf(v, WIN[(16 + k) * 64 + j], av[j]);
    }

    // ---- color layer 2: b = relu(a) @ WH ----
    float bv[64];
    #pragma unroll
    for (int j = 0; j < 64; ++j) bv[j] = 0.0f;
    #pragma unroll
    for (int k = 0; k < 64; ++k) {
        const float v = fmaxf(av[k], 0.0f);
        #pragma unroll
        for (int j = 0; j < 64; ++j) bv[j] = fmaf(v, WH[k * 64 + j], bv[j]);
    }

    // ---- color out: rgb = sigmoid(relu(b) @ WOUT) ----
    float r0 = 0.0f, r1 = 0.0f, r2 = 0.0f;
    #pragma unroll
    for (int k = 0; k < 64; ++k) {
        const float v = fmaxf(bv[k], 0.0f);
        r0 = fmaf(v, WOUT[k * 3 + 0], r0);
        r1 = fmaf(v, WOUT[k * 3 + 1], r1);
        r2 = fmaf(v, WOUT[k * 3 + 2], r2);
    }
    out[n + 3 * i + 0] = 1.0f / (1.0f + __expf(-r0));
    out[n + 3 * i + 1] = 1.0f / (1.0f + __expf(-r1));
    out[n + 3 * i + 2] = 1.0f / (1.0f + __expf(-r2));
}

extern "C" void kernel_launch(void* const* d_in, const int* in_sizes, int n_in,
                              void* d_out, int out_size, void* d_ws, size_t ws_size,
                              hipStream_t stream)
{
    const float* x    = (const float*)d_in[0];
    const float* d    = (const float*)d_in[1];
    const float* tb   = (const float*)d_in[2];
    const float* w1   = (const float*)d_in[3];
    const float* w2   = (const float*)d_in[4];
    const float* win  = (const float*)d_in[5];
    const float* wh   = (const float*)d_in[6];
    const float* wout = (const float*)d_in[7];

    const int n = in_sizes[0] / 3;   // 262144

    ngp_main<<<n / 256, 256, 0, stream>>>(x, d, (const float2*)tb,
                                          w1, w2, win, wh, wout,
                                          (float*)d_out, n);
}